// Round 4
// baseline (167.252 us; speedup 1.0000x reference)
//
#include <hip/hip_runtime.h>
#include <hip/hip_bf16.h>

#define M_DIM 4096
#define N_DIM 4096
#define K_DIM 4096
#define BM 256
#define BN 256
#define BK 64
#define NTILES (K_DIM / BK)   // 64

typedef __attribute__((ext_vector_type(8))) short short8;
typedef __attribute__((ext_vector_type(4))) float float4v;

__device__ __forceinline__ unsigned short f2bf(float f) {
    return __builtin_bit_cast(unsigned short, __float2bfloat16(f));
}

__device__ __forceinline__ void gload_lds16(const unsigned short* gsrc, unsigned short* lds) {
    __builtin_amdgcn_global_load_lds(
        (const __attribute__((address_space(1))) unsigned int*)gsrc,
        (__attribute__((address_space(3))) unsigned int*)lds,
        16, 0, 0);
}

// compiler fence + raw barrier (no vmcnt drain — vmcnt counted manually)
#define BAR() do { asm volatile("" ::: "memory"); __builtin_amdgcn_s_barrier(); \
                   asm volatile("" ::: "memory"); } while (0)

// 16-MFMA quadrant: compile-time acc offsets (rule #20: no runtime indexing)
#define MFMA_Q(AR, BR, MO, NO)                                                   \
  do {                                                                           \
    __builtin_amdgcn_s_setprio(1);                                               \
    _Pragma("unroll") for (int mf = 0; mf < 4; ++mf)                             \
      _Pragma("unroll") for (int nf = 0; nf < 2; ++nf)                           \
        _Pragma("unroll") for (int kk = 0; kk < 2; ++kk)                         \
          acc[(MO) + mf][(NO) + nf] = __builtin_amdgcn_mfma_f32_16x16x32_bf16(   \
              AR[mf][kk], BR[nf][kk], acc[(MO) + mf][(NO) + nf], 0, 0, 0);       \
    __builtin_amdgcn_s_setprio(0);                                               \
  } while (0)

// ---------------- fp32 -> bf16 conversion pass ----------------
__global__ __launch_bounds__(256)
void cvt_fp32_bf16(const float* __restrict__ X, const float* __restrict__ W,
                   unsigned short* __restrict__ XB, unsigned short* __restrict__ WB) {
    const long per_mat = (long)M_DIM * K_DIM / 8;
    const long total   = 2 * per_mat;
    for (long u = (long)blockIdx.x * blockDim.x + threadIdx.x; u < total;
         u += (long)gridDim.x * blockDim.x) {
        const float* src;
        unsigned short* dst;
        long v;
        if (u < per_mat) { src = X; dst = XB; v = u; }
        else             { src = W; dst = WB; v = u - per_mat; }
        float4v a = *(const float4v*)(src + v * 8);
        float4v b = *(const float4v*)(src + v * 8 + 4);
        short8 o;
#pragma unroll
        for (int e = 0; e < 4; ++e) {
            o[e]     = (short)f2bf(a[e]);
            o[e + 4] = (short)f2bf(b[e]);
        }
        *(short8*)(dst + v * 8) = o;
    }
}

// ---------------- 256x256 8-phase bf16 GEMM, fragment-major LDS ----------------
// LDS: 8 regions x 16KB = 128KB. Region idx = mat*4 + half*2 + buf.
// Region = [128 rows][64 k] bf16, stored FRAGMENT-MAJOR: 2 rho sub-blocks
// (rows rho*64..+63) x 8 chunks of 512 shorts. Chunk c = rowgroup (c>>1),
// kgroup (c&1); within a chunk, lane l holds row (l&15), k (l>>4)*8 .. +8 —
// exactly one MFMA A/B fragment. ds_read_b128 = base + lane*16: conflict-free.
__global__ __launch_bounds__(512, 2)
void gemm_8ph(const unsigned short* __restrict__ XB, const unsigned short* __restrict__ WB,
              const float* __restrict__ Bv, float* __restrict__ O) {
    extern __shared__ unsigned short lds[];

    const int tid  = threadIdx.x;
    const int lane = tid & 63;
    const int wid  = tid >> 6;
    const int wm   = wid >> 2;   // 0..1 (M half)
    const int wn   = wid & 3;    // 0..3 (N quarter)

    // bijective XCD swizzle (nwg=256, %8==0)
    const int wg   = (blockIdx.x & 7) * 32 + (blockIdx.x >> 3);
    const int brow = (wg >> 4) * BM;
    const int bcol = (wg & 15) * BN;

    // staging source mapping (fragment-major): wave wid stages chunk wid of the
    // rho-block; lane l supplies row (wid>>1)*16 + (l&15), k (wid&1)*32 + (l>>4)*8
    const int srow_loc = (wid >> 1) * 16 + (lane & 15);
    const int skcol    = (wid & 1) * 32 + (lane >> 4) * 8;

    auto STAGE1 = [&](int mat, int half, int rho, int buf, int t) {
        const unsigned short* gsrc = (mat == 0)
            ? XB + (long)(brow + half * 128 + rho * 64 + srow_loc) * K_DIM + t * 64 + skcol
            : WB + (long)(bcol + half * 128 + rho * 64 + srow_loc) * K_DIM + t * 64 + skcol;
        unsigned short* reg = lds + (mat * 4 + half * 2 + buf) * 8192;
        gload_lds16(gsrc, reg + rho * 4096 + wid * 512);
    };

    auto LDA = [&](short8 (&dst)[4][2], int buf, int rho) {
        const unsigned short* base =
            lds + (wm * 2 + buf) * 8192 + rho * 4096 + lane * 8;
#pragma unroll
        for (int mf = 0; mf < 4; ++mf)
#pragma unroll
            for (int kk = 0; kk < 2; ++kk)
                dst[mf][kk] = *(const short8*)(base + (mf * 2 + kk) * 512);
    };
    auto LDB = [&](short8 (&dst)[2][2], int buf, int nh) {
        const unsigned short* base =
            lds + (4 + (wn >> 1) * 2 + buf) * 8192 + (wn & 1) * 4096 + lane * 8;
#pragma unroll
        for (int nf = 0; nf < 2; ++nf)
#pragma unroll
            for (int kk = 0; kk < 2; ++kk)
                dst[nf][kk] = *(const short8*)(base + ((nh * 2 + nf) * 2 + kk) * 512);
    };

    float4v acc[8][4] = {};
    short8 a0[4][2], a1[4][2], b0[2][2], b1[2][2];

    // ---- prologue: tile0 fully (8 sub-blocks) + tile1's A + B-rho0 (6) ----
    STAGE1(0, 0, 0, 0, 0); STAGE1(0, 1, 0, 0, 0);
    STAGE1(0, 0, 1, 0, 0); STAGE1(0, 1, 1, 0, 0);
    STAGE1(1, 0, 0, 0, 0); STAGE1(1, 1, 0, 0, 0);
    STAGE1(1, 0, 1, 0, 0); STAGE1(1, 1, 1, 0, 0);
    STAGE1(0, 0, 0, 1, 1); STAGE1(0, 1, 0, 1, 1);
    STAGE1(0, 0, 1, 1, 1); STAGE1(0, 1, 1, 1, 1);
    STAGE1(1, 0, 0, 1, 1); STAGE1(1, 1, 0, 1, 1);
    asm volatile("s_waitcnt vmcnt(6)" ::: "memory");  // tile0's 8 landed
    BAR();

    // ---- main loop: 2 tiles / iteration, 8 phases ----
    auto do_tile = [&](int buf, int t) {
        // P1: read A-rho0 + B-lo; stage B-rho1 of t+1 (other buffer)
        LDA(a0, buf, 0);
        LDB(b0, buf, 0);
        if (t + 1 < NTILES) { STAGE1(1, 0, 1, buf ^ 1, t + 1); STAGE1(1, 1, 1, buf ^ 1, t + 1); }
        BAR();
        MFMA_Q(a0, b0, 0, 0);
        BAR();
        // P2: read A-rho1; stage A-rho0 of t+2 (this buffer; rho0 reads done at P1)
        LDA(a1, buf, 1);
        if (t + 2 < NTILES) { STAGE1(0, 0, 0, buf, t + 2); STAGE1(0, 1, 0, buf, t + 2); }
        BAR();
        MFMA_Q(a1, b0, 4, 0);
        BAR();
        // P3: read B-hi; stage A-rho1 of t+2 (rho1 reads done at P2)
        LDB(b1, buf, 1);
        if (t + 2 < NTILES) { STAGE1(0, 0, 1, buf, t + 2); STAGE1(0, 1, 1, buf, t + 2); }
        BAR();
        MFMA_Q(a1, b1, 4, 2);
        BAR();
        // P4: all-register MFMA; stage B-rho0 of t+2 (B reads done at P3); counted vmcnt
        if (t + 2 < NTILES) { STAGE1(1, 0, 0, buf, t + 2); STAGE1(1, 1, 0, buf, t + 2); }
        BAR();
        MFMA_Q(a0, b1, 0, 2);
        if (t + 2 < NTILES) {
            asm volatile("s_waitcnt vmcnt(6)" ::: "memory");   // tile t+1 fully landed
        } else if (t + 1 < NTILES) {
            asm volatile("s_waitcnt vmcnt(0)" ::: "memory");   // tail drain
        }
        BAR();
    };

    for (int it = 0; it < NTILES / 2; ++it) {
        do_tile(0, 2 * it);
        do_tile(1, 2 * it + 1);
    }

    // ---- epilogue: bias + store (D: col = lane&15, row = (lane>>4)*4 + r) ----
#pragma unroll
    for (int nf = 0; nf < 4; ++nf) {
        const int col = bcol + wn * 64 + nf * 16 + (lane & 15);
        const float bias = Bv[col];
#pragma unroll
        for (int mf = 0; mf < 8; ++mf) {
            const int row0 = brow + wm * 128 + mf * 16 + (lane >> 4) * 4;
#pragma unroll
            for (int r = 0; r < 4; ++r)
                O[(long)(row0 + r) * N_DIM + col] = acc[mf][nf][r] + bias;
        }
    }
}

extern "C" void kernel_launch(void* const* d_in, const int* in_sizes, int n_in,
                              void* d_out, int out_size, void* d_ws, size_t ws_size,
                              hipStream_t stream) {
    const float* X  = (const float*)d_in[0];
    const float* W  = (const float*)d_in[1];
    const float* Bv = (const float*)d_in[2];
    float* O        = (float*)d_out;

    unsigned short* XB = (unsigned short*)d_ws;
    unsigned short* WB = XB + (size_t)M_DIM * K_DIM;

    hipFuncSetAttribute((const void*)gemm_8ph,
                        hipFuncAttributeMaxDynamicSharedMemorySize, 131072);

    hipLaunchKernelGGL(cvt_fp32_bf16, dim3(2048), dim3(256), 0, stream, X, W, XB, WB);
    hipLaunchKernelGGL(gemm_8ph, dim3((M_DIM / BM) * (N_DIM / BN)), dim3(512), 131072,
                       stream, XB, WB, Bv, O);
}